// Round 1
// baseline (810.339 us; speedup 1.0000x reference)
//
#include <hip/hip_runtime.h>
#include <hip/hip_bf16.h>

#define D_MODEL   768
#define N_CH      2
#define TWO_D     1536      // N_CH * D_MODEL
#define SEQ       1024
#define N_LOOPS   4
#define RANK      8
#define D_STATE   16
#define LORA_SCALE 2.0f
#define EPS       1e-6f

// ---------------- prep: W_in = base + 2 * (lora_B @ lora_A) ----------------
__global__ __launch_bounds__(256) void prep_win(
    const float* __restrict__ base, const float* __restrict__ lA,
    const float* __restrict__ lB, float* __restrict__ W)
{
    int idx = blockIdx.x * 256 + threadIdx.x;       // 0 .. 1536*768-1
    int r = idx / D_MODEL;
    int c = idx - r * D_MODEL;
    float acc = base[idx];
#pragma unroll
    for (int k = 0; k < RANK; ++k)
        acc += LORA_SCALE * lB[r * RANK + k] * lA[k * D_MODEL + c];
    W[idx] = acc;
}

// ------- prep: G_k[cd] = sum_s Re( (Cr+iCi) e^{ik*theta} (Br+iBi) ), k=0..3 -------
__global__ __launch_bounds__(256) void prep_g(
    const float* __restrict__ th, const float* __restrict__ Br,
    const float* __restrict__ Bi, const float* __restrict__ Cr,
    const float* __restrict__ Ci, float* __restrict__ G)
{
    int cd = blockIdx.x * 256 + threadIdx.x;        // 0 .. 1535
    if (cd >= TWO_D) return;
    float g0 = 0.f, g1 = 0.f, g2 = 0.f, g3 = 0.f;
    for (int s = 0; s < D_STATE; ++s) {
        int idx = cd * D_STATE + s;
        float t  = th[idx];
        float br = Br[idx], bi = Bi[idx];
        float cr = Cr[idx], ci = Ci[idx];
#pragma unroll
        for (int k = 0; k < 4; ++k) {
            float ck = cosf(k * t), sk = sinf(k * t);
            float er = ck * br - sk * bi;           // Re(e^{ik t} B)
            float ei = sk * br + ck * bi;           // Im(e^{ik t} B)
            float g  = cr * er - ci * ei;           // Re(C * e^{ik t} B)
            if (k == 0) g0 += g; else if (k == 1) g1 += g;
            else if (k == 2) g2 += g; else g3 += g;
        }
    }
    G[0 * TWO_D + cd] = g0;
    G[1 * TWO_D + cd] = g1;
    G[2 * TWO_D + cd] = g2;
    G[3 * TWO_D + cd] = g3;
}

// ---------------- tiled NT SGEMM: C[M,N] = A[M,K] * B[N,K]^T ----------------
#define BM 64
#define BN 64
#define BK 16
#define LDT 68   // padded LDS stride (keeps 16B alignment, spreads banks)

// GEMM1: A = x_prev + step_emb (fused), B = W_in.  M=1024 N=1536 K=768
__global__ __launch_bounds__(256) void gemm1_kernel(
    const float* __restrict__ X,     // [SEQ][D_MODEL]
    const float* __restrict__ emb,   // [D_MODEL]
    const float* __restrict__ W,     // [TWO_D][D_MODEL]
    float* __restrict__ C)           // [SEQ][TWO_D]
{
    __shared__ float As[BK][LDT];
    __shared__ float Bs[BK][LDT];
    const int K = D_MODEL, N = TWO_D;
    const int bm = blockIdx.y, bn = blockIdx.x;
    const int t  = threadIdx.x;
    const int tx = t & 15, ty = t >> 4;
    const int row4 = t >> 2;            // 0..63
    const int kq   = (t & 3) * 4;       // 0,4,8,12
    float acc[4][4] = {};
    for (int k0 = 0; k0 < K; k0 += BK) {
        {
            const float4 v = *reinterpret_cast<const float4*>(
                X + (size_t)(bm * BM + row4) * K + k0 + kq);
            const float4 e = *reinterpret_cast<const float4*>(emb + k0 + kq);
            As[kq + 0][row4] = v.x + e.x;
            As[kq + 1][row4] = v.y + e.y;
            As[kq + 2][row4] = v.z + e.z;
            As[kq + 3][row4] = v.w + e.w;
        }
        {
            const float4 v = *reinterpret_cast<const float4*>(
                W + (size_t)(bn * BN + row4) * K + k0 + kq);
            Bs[kq + 0][row4] = v.x;
            Bs[kq + 1][row4] = v.y;
            Bs[kq + 2][row4] = v.z;
            Bs[kq + 3][row4] = v.w;
        }
        __syncthreads();
#pragma unroll
        for (int kk = 0; kk < BK; ++kk) {
            float a[4], b[4];
#pragma unroll
            for (int i = 0; i < 4; ++i) a[i] = As[kk][ty * 4 + i];
#pragma unroll
            for (int j = 0; j < 4; ++j) b[j] = Bs[kk][tx * 4 + j];
#pragma unroll
            for (int i = 0; i < 4; ++i)
#pragma unroll
                for (int j = 0; j < 4; ++j)
                    acc[i][j] += a[i] * b[j];
        }
        __syncthreads();
    }
#pragma unroll
    for (int i = 0; i < 4; ++i) {
        int m = bm * BM + ty * 4 + i;
        float4 v = make_float4(acc[i][0], acc[i][1], acc[i][2], acc[i][3]);
        *reinterpret_cast<float4*>(C + (size_t)m * N + bn * BN + tx * 4) = v;
    }
}

// GEMM2: A = y (on-the-fly: sum_j G_{i-j} ⊙ x_in_j), B = out_proj_w.
// M=1024 N=768 K=1536
__global__ __launch_bounds__(256) void gemm2_kernel(
    const float* __restrict__ xin,   // [N_LOOPS][SEQ][TWO_D] (first nacc valid)
    const float* __restrict__ G,     // [4][TWO_D]
    const int nacc,                  // i+1
    const float* __restrict__ W,     // [D_MODEL][TWO_D]
    float* __restrict__ C)           // [SEQ][D_MODEL]
{
    __shared__ float As[BK][LDT];
    __shared__ float Bs[BK][LDT];
    const int K = TWO_D, N = D_MODEL;
    const int bm = blockIdx.y, bn = blockIdx.x;
    const int t  = threadIdx.x;
    const int tx = t & 15, ty = t >> 4;
    const int row4 = t >> 2;
    const int kq   = (t & 3) * 4;
    float acc[4][4] = {};
    for (int k0 = 0; k0 < K; k0 += BK) {
        {
            float4 s = make_float4(0.f, 0.f, 0.f, 0.f);
            const size_t rowoff = (size_t)(bm * BM + row4) * K + k0 + kq;
            for (int j = 0; j < nacc; ++j) {
                const float4 v = *reinterpret_cast<const float4*>(
                    xin + (size_t)j * SEQ * TWO_D + rowoff);
                const float4 g = *reinterpret_cast<const float4*>(
                    G + (size_t)(nacc - 1 - j) * TWO_D + k0 + kq);
                s.x += g.x * v.x; s.y += g.y * v.y;
                s.z += g.z * v.z; s.w += g.w * v.w;
            }
            As[kq + 0][row4] = s.x;
            As[kq + 1][row4] = s.y;
            As[kq + 2][row4] = s.z;
            As[kq + 3][row4] = s.w;
        }
        {
            const float4 v = *reinterpret_cast<const float4*>(
                W + (size_t)(bn * BN + row4) * K + k0 + kq);
            Bs[kq + 0][row4] = v.x;
            Bs[kq + 1][row4] = v.y;
            Bs[kq + 2][row4] = v.z;
            Bs[kq + 3][row4] = v.w;
        }
        __syncthreads();
#pragma unroll
        for (int kk = 0; kk < BK; ++kk) {
            float a[4], b[4];
#pragma unroll
            for (int i = 0; i < 4; ++i) a[i] = As[kk][ty * 4 + i];
#pragma unroll
            for (int j = 0; j < 4; ++j) b[j] = Bs[kk][tx * 4 + j];
#pragma unroll
            for (int i = 0; i < 4; ++i)
#pragma unroll
                for (int j = 0; j < 4; ++j)
                    acc[i][j] += a[i] * b[j];
        }
        __syncthreads();
    }
#pragma unroll
    for (int i = 0; i < 4; ++i) {
        int m = bm * BM + ty * 4 + i;
        float4 v = make_float4(acc[i][0], acc[i][1], acc[i][2], acc[i][3]);
        *reinterpret_cast<float4*>(C + (size_t)m * N + bn * BN + tx * 4) = v;
    }
}

// ---------- fused epilogue: out = rmsnorm(outpre)*mw ; x' = rmsnorm(h+out)*lw ----------
__device__ inline float block_sum256(float v) {
    __shared__ float sm[4];
#pragma unroll
    for (int off = 32; off > 0; off >>= 1) v += __shfl_down(v, off, 64);
    __syncthreads();
    if ((threadIdx.x & 63) == 0) sm[threadIdx.x >> 6] = v;
    __syncthreads();
    return sm[0] + sm[1] + sm[2] + sm[3];
}

__global__ __launch_bounds__(256) void norm_kernel(
    const float* __restrict__ outpre,  // [SEQ][D_MODEL]
    const float* __restrict__ xprev,   // [SEQ][D_MODEL]
    const float* __restrict__ emb,     // [D_MODEL]
    const float* __restrict__ mw,
    const float* __restrict__ lw,
    float* __restrict__ xout)          // [SEQ][D_MODEL]
{
    const int r = blockIdx.x;
    const int t = threadIdx.x;
    float op[3], h[3];
    float ss = 0.f;
#pragma unroll
    for (int j = 0; j < 3; ++j) {
        int d = t + j * 256;
        op[j] = outpre[(size_t)r * D_MODEL + d];
        h[j]  = xprev[(size_t)r * D_MODEL + d] + emb[d];
        ss += op[j] * op[j];
    }
    ss = block_sum256(ss);
    const float rs1 = rsqrtf(ss * (1.0f / D_MODEL) + EPS);
    float tt[3];
    float ss2 = 0.f;
#pragma unroll
    for (int j = 0; j < 3; ++j) {
        int d = t + j * 256;
        tt[j] = h[j] + op[j] * rs1 * mw[d];
        ss2 += tt[j] * tt[j];
    }
    ss2 = block_sum256(ss2);
    const float rs2 = rsqrtf(ss2 * (1.0f / D_MODEL) + EPS);
#pragma unroll
    for (int j = 0; j < 3; ++j) {
        int d = t + j * 256;
        xout[(size_t)r * D_MODEL + d] = tt[j] * rs2 * lw[d];
    }
}

// ------------------------------------------------------------------
extern "C" void kernel_launch(void* const* d_in, const int* in_sizes, int n_in,
                              void* d_out, int out_size, void* d_ws, size_t ws_size,
                              hipStream_t stream) {
    const float* x            = (const float*)d_in[0];
    const float* in_proj_base = (const float*)d_in[1];
    const float* lora_A       = (const float*)d_in[2];
    const float* lora_B       = (const float*)d_in[3];
    const float* A_theta      = (const float*)d_in[4];
    const float* B_real       = (const float*)d_in[5];
    const float* B_imag       = (const float*)d_in[6];
    const float* C_real       = (const float*)d_in[7];
    const float* C_imag       = (const float*)d_in[8];
    const float* out_proj_w   = (const float*)d_in[9];
    const float* mixer_w      = (const float*)d_in[10];
    const float* loop_w       = (const float*)d_in[11];
    const float* step_emb     = (const float*)d_in[12];
    float* out = (float*)d_out;
    float* ws  = (float*)d_ws;

    float* W      = ws;                         // 1536*768       = 1179648
    float* G      = W + (size_t)TWO_D * D_MODEL;        // 4*1536 = 6144
    float* xin    = G + 4 * TWO_D;              // 4*1024*1536    = 6291456
    float* xbuf   = xin + (size_t)N_LOOPS * SEQ * TWO_D;   // 786432
    float* outpre = xbuf + (size_t)SEQ * D_MODEL;          // 786432

    prep_win<<<(TWO_D * D_MODEL) / 256, 256, 0, stream>>>(in_proj_base, lora_A, lora_B, W);
    prep_g<<<(TWO_D + 255) / 256, 256, 0, stream>>>(A_theta, B_real, B_imag, C_real, C_imag, G);

    for (int i = 0; i < N_LOOPS; ++i) {
        const float* xprev = (i == 0) ? x : xbuf;
        float* xout = (i == N_LOOPS - 1) ? out : xbuf;
        gemm1_kernel<<<dim3(TWO_D / BN, SEQ / BM), 256, 0, stream>>>(
            xprev, step_emb + i * D_MODEL, W, xin + (size_t)i * SEQ * TWO_D);
        gemm2_kernel<<<dim3(D_MODEL / BN, SEQ / BM), 256, 0, stream>>>(
            xin, G, i + 1, out_proj_w, outpre);
        norm_kernel<<<SEQ, 256, 0, stream>>>(
            outpre, xprev, step_emb + i * D_MODEL, mixer_w, loop_w, xout);
    }
}

// Round 2
// 244.508 us; speedup vs baseline: 3.3142x; 3.3142x over previous
//
#include <hip/hip_runtime.h>

#define D_MODEL   768
#define TWO_D     1536
#define SEQ       1024
#define N_LOOPS   4
#define RANK      8
#define D_STATE   16
#define EPS       1e-6f

typedef unsigned short u16;
typedef short s16x8 __attribute__((ext_vector_type(8)));
typedef unsigned short u16x4 __attribute__((ext_vector_type(4)));
typedef float f32x4 __attribute__((ext_vector_type(4)));

__device__ inline u16 f2bf(float f) {
    union { float f; unsigned u; } v; v.f = f;
    unsigned r = v.u + 0x7fffu + ((v.u >> 16) & 1u);   // RNE
    return (u16)(r >> 16);
}
__device__ inline float bf2f(u16 b) {
    union { unsigned u; float f; } v; v.u = ((unsigned)b) << 16;
    return v.f;
}

// ---------------- prep: W_in = bf16(base + 2 * (lora_B @ lora_A)) ----------------
__global__ __launch_bounds__(256) void prep_win(
    const float* __restrict__ base, const float* __restrict__ lA,
    const float* __restrict__ lB, u16* __restrict__ W)
{
    int idx = blockIdx.x * 256 + threadIdx.x;       // 0 .. 1536*768-1
    int r = idx / D_MODEL;
    int c = idx - r * D_MODEL;
    float acc = base[idx];
#pragma unroll
    for (int k = 0; k < RANK; ++k)
        acc += 2.0f * lB[r * RANK + k] * lA[k * D_MODEL + c];
    W[idx] = f2bf(acc);
}

// ---------------- prep: bf16 copy of out_proj_w ----------------
__global__ __launch_bounds__(256) void prep_wout(
    const float* __restrict__ src, u16* __restrict__ dst)
{
    int i4 = blockIdx.x * 256 + threadIdx.x;        // *4 elems
    const float4 v = *reinterpret_cast<const float4*>(src + (size_t)i4 * 4);
    u16x4 o; o.x = f2bf(v.x); o.y = f2bf(v.y); o.z = f2bf(v.z); o.w = f2bf(v.w);
    *reinterpret_cast<u16x4*>(dst + (size_t)i4 * 4) = o;
}

// ------- prep: G_k[cd] = sum_s Re( (Cr+iCi) e^{ik*theta} (Br+iBi) ), k=0..3 -------
__global__ __launch_bounds__(256) void prep_g(
    const float* __restrict__ th, const float* __restrict__ Br,
    const float* __restrict__ Bi, const float* __restrict__ Cr,
    const float* __restrict__ Ci, float* __restrict__ G)
{
    int cd = blockIdx.x * 256 + threadIdx.x;        // 0 .. 1535
    if (cd >= TWO_D) return;
    float g0 = 0.f, g1 = 0.f, g2 = 0.f, g3 = 0.f;
    for (int s = 0; s < D_STATE; ++s) {
        int idx = cd * D_STATE + s;
        float t  = th[idx];
        float br = Br[idx], bi = Bi[idx];
        float cr = Cr[idx], ci = Ci[idx];
#pragma unroll
        for (int k = 0; k < 4; ++k) {
            float ck = cosf(k * t), sk = sinf(k * t);
            float er = ck * br - sk * bi;
            float ei = sk * br + ck * bi;
            float g  = cr * er - ci * ei;
            if (k == 0) g0 += g; else if (k == 1) g1 += g;
            else if (k == 2) g2 += g; else g3 += g;
        }
    }
    G[0 * TWO_D + cd] = g0;
    G[1 * TWO_D + cd] = g1;
    G[2 * TWO_D + cd] = g2;
    G[3 * TWO_D + cd] = g3;
}

// ---------------- init: h0 = x + emb0 (f32 + bf16) ----------------
__global__ __launch_bounds__(256) void init_h(
    const float* __restrict__ x, const float* __restrict__ emb,
    float* __restrict__ hf, u16* __restrict__ hb)
{
    int i4 = blockIdx.x * 256 + threadIdx.x;        // *4 elems, 1024*768/4
    int base = i4 * 4;
    int d = base % D_MODEL;
    const float4 v = *reinterpret_cast<const float4*>(x + base);
    const float4 e = *reinterpret_cast<const float4*>(emb + d);
    float4 h = make_float4(v.x + e.x, v.y + e.y, v.z + e.z, v.w + e.w);
    *reinterpret_cast<float4*>(hf + base) = h;
    u16x4 o; o.x = f2bf(h.x); o.y = f2bf(h.y); o.z = f2bf(h.z); o.w = f2bf(h.w);
    *reinterpret_cast<u16x4*>(hb + base) = o;
}

// ---------------- bf16 NT MFMA GEMM: C[M,N] = A[M,K] * B[N,K]^T ----------------
// 64x64 tile, BK=64, 256 threads (4 waves, each a 32x32 quadrant of 2x2 16x16 frags)
template<int K, bool OUT_BF16>
__global__ __launch_bounds__(256) void gemm_nt(
    const u16* __restrict__ A, const u16* __restrict__ B,
    void* __restrict__ Cv, const int N)
{
    __shared__ u16 Al[64][72];   // +8 pad: row stride 144B = 36 banks -> 2-way max
    __shared__ u16 Bl[64][72];
    const int t  = threadIdx.x;
    const int bm = blockIdx.y, bn = blockIdx.x;
    const int lane = t & 63, w = t >> 6;
    const int wr = w >> 1, wc = w & 1;
    const int lr = lane & 15, kg = lane >> 4;

    // staging: 512 16B chunks per operand tile; thread t owns chunks t and t+256
    const int r0 = t >> 3;              // 0..31
    const int q0 = t & 7;               // 16B column within row
    const u16* Ag0 = A + (size_t)(bm * 64 + r0)      * K + q0 * 8;
    const u16* Ag1 = A + (size_t)(bm * 64 + r0 + 32) * K + q0 * 8;
    const u16* Bg0 = B + (size_t)(bn * 64 + r0)      * K + q0 * 8;
    const u16* Bg1 = B + (size_t)(bn * 64 + r0 + 32) * K + q0 * 8;

    uint4 ra0 = *reinterpret_cast<const uint4*>(Ag0);
    uint4 ra1 = *reinterpret_cast<const uint4*>(Ag1);
    uint4 rb0 = *reinterpret_cast<const uint4*>(Bg0);
    uint4 rb1 = *reinterpret_cast<const uint4*>(Bg1);

    f32x4 acc[2][2] = {};
    const int NKT = K / 64;
    for (int kt = 0; kt < NKT; ++kt) {
        *reinterpret_cast<uint4*>(&Al[r0][q0 * 8])      = ra0;
        *reinterpret_cast<uint4*>(&Al[r0 + 32][q0 * 8]) = ra1;
        *reinterpret_cast<uint4*>(&Bl[r0][q0 * 8])      = rb0;
        *reinterpret_cast<uint4*>(&Bl[r0 + 32][q0 * 8]) = rb1;
        __syncthreads();
        if (kt + 1 < NKT) {                  // issue next-tile loads; fly during MFMA
            const int ko = (kt + 1) * 64;
            ra0 = *reinterpret_cast<const uint4*>(Ag0 + ko);
            ra1 = *reinterpret_cast<const uint4*>(Ag1 + ko);
            rb0 = *reinterpret_cast<const uint4*>(Bg0 + ko);
            rb1 = *reinterpret_cast<const uint4*>(Bg1 + ko);
        }
#pragma unroll
        for (int ks = 0; ks < 2; ++ks) {
            const int ko = ks * 32 + kg * 8;
            s16x8 a0 = *reinterpret_cast<const s16x8*>(&Al[wr * 32 + lr][ko]);
            s16x8 a1 = *reinterpret_cast<const s16x8*>(&Al[wr * 32 + 16 + lr][ko]);
            s16x8 b0 = *reinterpret_cast<const s16x8*>(&Bl[wc * 32 + lr][ko]);
            s16x8 b1 = *reinterpret_cast<const s16x8*>(&Bl[wc * 32 + 16 + lr][ko]);
            acc[0][0] = __builtin_amdgcn_mfma_f32_16x16x32_bf16(a0, b0, acc[0][0], 0, 0, 0);
            acc[0][1] = __builtin_amdgcn_mfma_f32_16x16x32_bf16(a0, b1, acc[0][1], 0, 0, 0);
            acc[1][0] = __builtin_amdgcn_mfma_f32_16x16x32_bf16(a1, b0, acc[1][0], 0, 0, 0);
            acc[1][1] = __builtin_amdgcn_mfma_f32_16x16x32_bf16(a1, b1, acc[1][1], 0, 0, 0);
        }
        __syncthreads();
    }
    // epilogue: C col = lane&15, row = (lane>>4)*4 + reg  [m89-verified]
    const int crow0 = bm * 64 + wr * 32 + kg * 4;
    const int ccol0 = bn * 64 + wc * 32 + lr;
#pragma unroll
    for (int m = 0; m < 2; ++m)
#pragma unroll
        for (int n = 0; n < 2; ++n)
#pragma unroll
            for (int r = 0; r < 4; ++r) {
                const int row = crow0 + m * 16 + r;
                const int col = ccol0 + n * 16;
                const float v = acc[m][n][r];
                if (OUT_BF16) ((u16*)Cv)[(size_t)row * N + col] = f2bf(v);
                else          ((float*)Cv)[(size_t)row * N + col] = v;
            }
}

// ---------------- y = sum_j G[i-j] ⊙ x_in_j  (bf16 in/out, f32 math) ----------------
__global__ __launch_bounds__(256) void y_kernel(
    const u16* __restrict__ xin,     // [N_LOOPS][SEQ][TWO_D]
    const float* __restrict__ G,     // [4][TWO_D]
    const int nacc, u16* __restrict__ y)
{
    int i4 = blockIdx.x * 256 + threadIdx.x;        // 0 .. 1024*1536/4-1
    int base = i4 * 4;
    int cd = base % TWO_D;
    float s0 = 0.f, s1 = 0.f, s2 = 0.f, s3 = 0.f;
    for (int j = 0; j < nacc; ++j) {
        u16x4 v = *reinterpret_cast<const u16x4*>(&xin[(size_t)j * SEQ * TWO_D + base]);
        const float4 g = *reinterpret_cast<const float4*>(&G[(size_t)(nacc - 1 - j) * TWO_D + cd]);
        s0 += bf2f(v.x) * g.x; s1 += bf2f(v.y) * g.y;
        s2 += bf2f(v.z) * g.z; s3 += bf2f(v.w) * g.w;
    }
    u16x4 o; o.x = f2bf(s0); o.y = f2bf(s1); o.z = f2bf(s2); o.w = f2bf(s3);
    *reinterpret_cast<u16x4*>(&y[base]) = o;
}

// ---------- fused epilogue: out = rmsnorm(outpre)*mw ; x' = rmsnorm(h+out)*lw ----------
__device__ inline float block_sum256(float v) {
    __shared__ float sm[4];
#pragma unroll
    for (int off = 32; off > 0; off >>= 1) v += __shfl_down(v, off, 64);
    __syncthreads();
    if ((threadIdx.x & 63) == 0) sm[threadIdx.x >> 6] = v;
    __syncthreads();
    return sm[0] + sm[1] + sm[2] + sm[3];
}

__global__ __launch_bounds__(256) void norm_kernel(
    const float* __restrict__ outpre,  // [SEQ][D_MODEL]
    const float* __restrict__ hprev,   // [SEQ][D_MODEL]  (= x_prev + emb_i)
    const float* __restrict__ mw,
    const float* __restrict__ lw,
    const float* __restrict__ embn,    // next step_emb, or nullptr on last loop
    float* __restrict__ dstf,          // hnext (f32) or final out
    u16* __restrict__ dstb)            // hnext (bf16) or nullptr
{
    const int r = blockIdx.x;
    const int t = threadIdx.x;
    const size_t ro = (size_t)r * D_MODEL;
    float op[3], h[3];
    float ss = 0.f;
#pragma unroll
    for (int j = 0; j < 3; ++j) {
        int d = t + j * 256;
        op[j] = outpre[ro + d];
        h[j]  = hprev[ro + d];
        ss += op[j] * op[j];
    }
    ss = block_sum256(ss);
    const float rs1 = rsqrtf(ss * (1.0f / D_MODEL) + EPS);
    float tt[3];
    float ss2 = 0.f;
#pragma unroll
    for (int j = 0; j < 3; ++j) {
        int d = t + j * 256;
        tt[j] = h[j] + op[j] * rs1 * mw[d];
        ss2 += tt[j] * tt[j];
    }
    ss2 = block_sum256(ss2);
    const float rs2 = rsqrtf(ss2 * (1.0f / D_MODEL) + EPS);
#pragma unroll
    for (int j = 0; j < 3; ++j) {
        int d = t + j * 256;
        float xo = tt[j] * rs2 * lw[d];
        if (embn != nullptr) {
            float hn = xo + embn[d];
            dstf[ro + d] = hn;
            dstb[ro + d] = f2bf(hn);
        } else {
            dstf[ro + d] = xo;
        }
    }
}

// ------------------------------------------------------------------
extern "C" void kernel_launch(void* const* d_in, const int* in_sizes, int n_in,
                              void* d_out, int out_size, void* d_ws, size_t ws_size,
                              hipStream_t stream) {
    const float* x            = (const float*)d_in[0];
    const float* in_proj_base = (const float*)d_in[1];
    const float* lora_A       = (const float*)d_in[2];
    const float* lora_B       = (const float*)d_in[3];
    const float* A_theta      = (const float*)d_in[4];
    const float* B_real       = (const float*)d_in[5];
    const float* B_imag       = (const float*)d_in[6];
    const float* C_real       = (const float*)d_in[7];
    const float* C_imag       = (const float*)d_in[8];
    const float* out_proj_w   = (const float*)d_in[9];
    const float* mixer_w      = (const float*)d_in[10];
    const float* loop_w       = (const float*)d_in[11];
    const float* step_emb     = (const float*)d_in[12];
    float* out = (float*)d_out;

    char* p = (char*)d_ws;
    u16*   Wbf    = (u16*)p;                       p += (size_t)TWO_D * D_MODEL * 2;     // 2.36 MB
    u16*   Woutbf = (u16*)p;                       p += (size_t)D_MODEL * TWO_D * 2;     // 2.36 MB
    float* G      = (float*)p;                     p += (size_t)4 * TWO_D * 4;           // 24 KB
    u16*   xin    = (u16*)p;                       p += (size_t)N_LOOPS * SEQ * TWO_D * 2; // 12.6 MB
    u16*   ybf    = (u16*)p;                       p += (size_t)SEQ * TWO_D * 2;         // 3.1 MB
    float* hAf    = (float*)p;                     p += (size_t)SEQ * D_MODEL * 4;       // 3.1 MB
    float* hBf    = (float*)p;                     p += (size_t)SEQ * D_MODEL * 4;       // 3.1 MB
    u16*   hbf    = (u16*)p;                       p += (size_t)SEQ * D_MODEL * 2;       // 1.6 MB
    float* outpre = (float*)p;                     p += (size_t)SEQ * D_MODEL * 4;       // 3.1 MB
    // total ~31.5 MB (< the 36.2 MB used successfully in round 1)

    prep_win<<<(TWO_D * D_MODEL) / 256, 256, 0, stream>>>(in_proj_base, lora_A, lora_B, Wbf);
    prep_wout<<<(D_MODEL * TWO_D / 4) / 256, 256, 0, stream>>>(out_proj_w, Woutbf);
    prep_g<<<(TWO_D + 255) / 256, 256, 0, stream>>>(A_theta, B_real, B_imag, C_real, C_imag, G);
    init_h<<<(SEQ * D_MODEL / 4) / 256, 256, 0, stream>>>(x, step_emb, hAf, hbf);

    float* hcur = hAf;
    float* hnxt = hBf;
    for (int i = 0; i < N_LOOPS; ++i) {
        const bool last = (i == N_LOOPS - 1);
        gemm_nt<D_MODEL, true><<<dim3(TWO_D / 64, SEQ / 64), 256, 0, stream>>>(
            hbf, Wbf, (void*)(xin + (size_t)i * SEQ * TWO_D), TWO_D);
        y_kernel<<<(SEQ * TWO_D / 4) / 256, 256, 0, stream>>>(xin, G, i + 1, ybf);
        gemm_nt<TWO_D, false><<<dim3(D_MODEL / 64, SEQ / 64), 256, 0, stream>>>(
            ybf, Woutbf, (void*)outpre, D_MODEL);
        norm_kernel<<<SEQ, 256, 0, stream>>>(
            outpre, hcur, mixer_w, loop_w,
            last ? nullptr : (step_emb + (size_t)(i + 1) * D_MODEL),
            last ? out : hnxt,
            last ? nullptr : hbf);
        float* tmp = hcur; hcur = hnxt; hnxt = tmp;
    }
}